// Round 3
// baseline (21.000 us; speedup 1.0000x reference)
//
#include <hip/hip_runtime.h>
#include <math.h>

// C=8, V=12, D=64, B=32768
#define NC 8
#define NV 12
#define ND 64
#define NB 32768
#define NROWS 96            // C*V table rows
#define RSW 68              // LDS row stride in 32-bit words (64 data + 4 pad)
#define OUT_LOSS 65536
#define OUT_PW   65537

__device__ __forceinline__ unsigned bf16rne(float x) {
    const unsigned u = __float_as_uint(x);
    return (u + 0x7FFFu + ((u >> 16) & 1u)) >> 16;
}

// softplus via native exp2/log2 pipes: ln(1+e^x) = ln2 * log2(1 + 2^(x*log2e))
__device__ __forceinline__ float fast_softplus(float x) {
    const float t = __builtin_exp2f(x * 1.44269504f);
    return 0.69314718f * __builtin_log2f(1.0f + t);
}

// ---- 512 blocks x 512 threads: 2 blocks/CU, 4 waves/SIMD; 1 b per thread-group ----
__global__ __launch_bounds__(512, 4) void fm_main(
    const int*   __restrict__ idx,    // [C,B]
    const float* __restrict__ label,  // [B,2]
    const float* __restrict__ posw,   // [B,2]
    const float* __restrict__ meant,  // [C,V,D]
    const float* __restrict__ stdt,   // [C,V,D]
    const float* __restrict__ act,    // [2,D]
    const float* __restrict__ noise,  // [B*D]
    float*       __restrict__ out)
{
    __shared__ unsigned tab[NROWS * RSW];  // word = bf16(mu) | bf16(softplus*0.01)<<16
    __shared__ float wloss[8];

    const int tid = threadIdx.x;

    // stage table: 6144 elems, float4-vectorized, fused fast-softplus*0.01, bf16-packed
    for (int i = tid * 4; i < NROWS * ND; i += 512 * 4) {
        const float4 mu4 = *(const float4*)(meant + i);
        const float4 sd4 = *(const float4*)(stdt + i);
        const int r = i >> 6, d = i & 63;
        uint4 w;
        w.x = bf16rne(mu4.x) | (bf16rne(fast_softplus(sd4.x) * 0.01f) << 16);
        w.y = bf16rne(mu4.y) | (bf16rne(fast_softplus(sd4.y) * 0.01f) << 16);
        w.z = bf16rne(mu4.z) | (bf16rne(fast_softplus(sd4.z) * 0.01f) << 16);
        w.w = bf16rne(mu4.w) | (bf16rne(fast_softplus(sd4.w) * 0.01f) << 16);
        *(uint4*)(&tab[r * RSW + d]) = w;
    }
    __syncthreads();

    const int lane = tid & 63;
    const int wave = tid >> 6;
    const int m    = lane & 7;    // d-octet: owns d = 8m..8m+7
    const int bsub = lane >> 3;   // which of the wave's 8 b's
    const int b    = (blockIdx.x * 8 + wave) * 8 + bsub;   // 0..32767

    const float4 a0l = *(const float4*)(act + 8*m);
    const float4 a0h = *(const float4*)(act + 8*m + 4);
    const float4 a1l = *(const float4*)(act + ND + 8*m);
    const float4 a1h = *(const float4*)(act + ND + 8*m + 4);

    const float4 vl = *(const float4*)(noise + b * ND + 8*m);
    const float4 vh = *(const float4*)(noise + b * ND + 8*m + 4);

    float s0=0,s1=0,s2=0,s3=0,s4=0,s5=0,s6=0,s7=0;
    float esq = 0.f;

    #pragma unroll
    for (int c = 0; c < NC; ++c) {
        const int g = idx[c * NB + b];                  // uniform across the 8-lane group
        const unsigned* rp = &tab[(c * NV + g) * RSW + 8*m];
        const uint4 w0 = *(const uint4*)(rp);
        const uint4 w1 = *(const uint4*)(rp + 4);
#define EMB(W, VV, SS) { \
        const float mu_ = __uint_as_float((W) << 16); \
        const float sp_ = __uint_as_float((W) & 0xFFFF0000u); \
        const float e_  = fmaf(sp_, (VV), mu_); \
        SS += e_; esq = fmaf(e_, e_, esq); }
        EMB(w0.x, vl.x, s0) EMB(w0.y, vl.y, s1) EMB(w0.z, vl.z, s2) EMB(w0.w, vl.w, s3)
        EMB(w1.x, vh.x, s4) EMB(w1.y, vh.y, s5) EMB(w1.z, vh.z, s6) EMB(w1.w, vh.w, s7)
#undef EMB
    }

    // 4 partials for this b's d-octet
    float r0 = s0*s0+s1*s1+s2*s2+s3*s3+s4*s4+s5*s5+s6*s6+s7*s7;  // ||s||^2 part
    float r1 = esq;                                              // sum e^2 part
    float r2 = s0*a0l.x+s1*a0l.y+s2*a0l.z+s3*a0l.w+s4*a0h.x+s5*a0h.y+s6*a0h.z+s7*a0h.w;
    float r3 = s0*a1l.x+s1*a1l.y+s2*a1l.z+s3*a1l.w+s4*a1h.x+s5*a1h.y+s6*a1h.z+s7*a1h.w;

    // reduce across the 8-lane d-octet group (xor masks stay in lane bits 0-2)
    #pragma unroll
    for (int off = 1; off <= 4; off <<= 1) {
        r0 += __shfl_xor(r0, off, 64);
        r1 += __shfl_xor(r1, off, 64);
        r2 += __shfl_xor(r2, off, 64);
        r3 += __shfl_xor(r3, off, 64);
    }

    float lossacc = 0.f;
    if (m == 0) {
        const float2 lb = *(const float2*)(label + 2*b);
        const float2 pw = *(const float2*)(posw + 2*b);
        ((float2*)out)[b] = make_float2(r2, r3);
        out[OUT_PW + b]   = 0.5f * (r0 - r1);
        const float d0 = r2 - lb.x, d1 = r3 - lb.y;
        lossacc = pw.x*d0*d0 + pw.y*d1*d1;
    }

    // reduce loss across bsub bits (lane bits 3-5), then across waves, one atomic/block
    #pragma unroll
    for (int off = 8; off <= 32; off <<= 1) lossacc += __shfl_xor(lossacc, off, 64);
    if (lane == 0) wloss[wave] = lossacc;
    __syncthreads();
    if (tid == 0) {
        float s = 0.f;
        #pragma unroll
        for (int i = 0; i < 8; ++i) s += wloss[i];
        atomicAdd(out + OUT_LOSS, s * (1.0f / (float)NB));
    }
}

extern "C" void kernel_launch(void* const* d_in, const int* in_sizes, int n_in,
                              void* d_out, int out_size, void* d_ws, size_t ws_size,
                              hipStream_t stream) {
    const int*   idx   = (const int*)d_in[0];
    const float* label = (const float*)d_in[1];
    const float* posw  = (const float*)d_in[2];
    const float* meant = (const float*)d_in[3];
    const float* stdt  = (const float*)d_in[4];
    const float* act   = (const float*)d_in[5];
    const float* noise = (const float*)d_in[6];
    float* out = (float*)d_out;

    hipMemsetAsync(out + OUT_LOSS, 0, sizeof(float), stream);
    fm_main<<<512, 512, 0, stream>>>(idx, label, posw, meant, stdt, act, noise, out);
}

// Round 4
// 12.505 us; speedup vs baseline: 1.6793x; 1.6793x over previous
//
#include <hip/hip_runtime.h>
#include <math.h>

// C=8, V=12, D=64, B=32768
#define NC 8
#define NV 12
#define ND 64
#define NB 32768
#define NROWS 96            // C*V table rows
#define RSW 68              // LDS row stride in 32-bit words (64 data + 4 pad)
#define OUT_LOSS 65536
#define OUT_PW   65537

__device__ __forceinline__ unsigned bf16rne(float x) {
    const unsigned u = __float_as_uint(x);
    return (u + 0x7FFFu + ((u >> 16) & 1u)) >> 16;
}

// softplus via native exp2/log2 pipes: ln(1+e^x) = ln2 * log2(1 + 2^(x*log2e))
__device__ __forceinline__ float fast_softplus(float x) {
    const float t = __builtin_exp2f(x * 1.44269504f);
    return 0.69314718f * __builtin_log2f(1.0f + t);
}

// ---- 256 blocks x 1024 threads: 1 block/CU, 4 waves/SIMD, stage table ONCE per CU ----
__global__ __launch_bounds__(1024, 4) void fm_main(
    const int*   __restrict__ idx,    // [C,B]
    const float* __restrict__ label,  // [B,2]
    const float* __restrict__ posw,   // [B,2]
    const float* __restrict__ meant,  // [C,V,D]
    const float* __restrict__ stdt,   // [C,V,D]
    const float* __restrict__ act,    // [2,D]
    const float* __restrict__ noise,  // [B*D]
    float*       __restrict__ out,
    float*       __restrict__ partial)
{
    __shared__ unsigned tab[NROWS * RSW];  // word = bf16(mu) | bf16(softplus*0.01)<<16
    __shared__ float wloss[16];

    const int tid  = threadIdx.x;
    const int lane = tid & 63;
    const int wave = tid >> 6;
    const int m    = lane & 7;    // d-octet: owns d = 8m..8m+7
    const int bsub = lane >> 3;   // which of the wave's 8 b's
    const int b    = blockIdx.x * 128 + wave * 8 + bsub;   // 0..32767

    // ---- issue ALL global loads early; latency drains under staging ----
    int g[NC];
    #pragma unroll
    for (int c = 0; c < NC; ++c) g[c] = idx[c * NB + b];

    const float4 vl = *(const float4*)(noise + b * ND + 8*m);
    const float4 vh = *(const float4*)(noise + b * ND + 8*m + 4);

    const float4 a0l = *(const float4*)(act + 8*m);
    const float4 a0h = *(const float4*)(act + 8*m + 4);
    const float4 a1l = *(const float4*)(act + ND + 8*m);
    const float4 a1h = *(const float4*)(act + ND + 8*m + 4);

    float2 lb = make_float2(0.f, 0.f), pw = make_float2(0.f, 0.f);
    if (m == 0) {
        lb = *(const float2*)(label + 2*b);
        pw = *(const float2*)(posw + 2*b);
    }

    // ---- stage table: 6144 elems, float4-vectorized, fast-softplus*0.01, bf16-packed ----
    for (int i = tid * 4; i < NROWS * ND; i += 1024 * 4) {
        const float4 mu4 = *(const float4*)(meant + i);
        const float4 sd4 = *(const float4*)(stdt + i);
        const int r = i >> 6, d = i & 63;
        uint4 w;
        w.x = bf16rne(mu4.x) | (bf16rne(fast_softplus(sd4.x) * 0.01f) << 16);
        w.y = bf16rne(mu4.y) | (bf16rne(fast_softplus(sd4.y) * 0.01f) << 16);
        w.z = bf16rne(mu4.z) | (bf16rne(fast_softplus(sd4.z) * 0.01f) << 16);
        w.w = bf16rne(mu4.w) | (bf16rne(fast_softplus(sd4.w) * 0.01f) << 16);
        *(uint4*)(&tab[r * RSW + d]) = w;
    }
    __syncthreads();

    float s0=0,s1=0,s2=0,s3=0,s4=0,s5=0,s6=0,s7=0;
    float esq = 0.f;

    #pragma unroll
    for (int c = 0; c < NC; ++c) {
        const unsigned* rp = &tab[(c * NV + g[c]) * RSW + 8*m];
        const uint4 w0 = *(const uint4*)(rp);
        const uint4 w1 = *(const uint4*)(rp + 4);
#define EMB(W, VV, SS) { \
        const float mu_ = __uint_as_float((W) << 16); \
        const float sp_ = __uint_as_float((W) & 0xFFFF0000u); \
        const float e_  = fmaf(sp_, (VV), mu_); \
        SS += e_; esq = fmaf(e_, e_, esq); }
        EMB(w0.x, vl.x, s0) EMB(w0.y, vl.y, s1) EMB(w0.z, vl.z, s2) EMB(w0.w, vl.w, s3)
        EMB(w1.x, vh.x, s4) EMB(w1.y, vh.y, s5) EMB(w1.z, vh.z, s6) EMB(w1.w, vh.w, s7)
#undef EMB
    }

    // 4 partials for this b's d-octet
    float r0 = s0*s0+s1*s1+s2*s2+s3*s3+s4*s4+s5*s5+s6*s6+s7*s7;  // ||s||^2 part
    float r1 = esq;                                              // sum e^2 part
    float r2 = s0*a0l.x+s1*a0l.y+s2*a0l.z+s3*a0l.w+s4*a0h.x+s5*a0h.y+s6*a0h.z+s7*a0h.w;
    float r3 = s0*a1l.x+s1*a1l.y+s2*a1l.z+s3*a1l.w+s4*a1h.x+s5*a1h.y+s6*a1h.z+s7*a1h.w;

    // reduce across the 8-lane d-octet group (xor masks stay in lane bits 0-2)
    #pragma unroll
    for (int off = 1; off <= 4; off <<= 1) {
        r0 += __shfl_xor(r0, off, 64);
        r1 += __shfl_xor(r1, off, 64);
        r2 += __shfl_xor(r2, off, 64);
        r3 += __shfl_xor(r3, off, 64);
    }

    float lossacc = 0.f;
    if (m == 0) {
        ((float2*)out)[b] = make_float2(r2, r3);
        out[OUT_PW + b]   = 0.5f * (r0 - r1);
        const float d0 = r2 - lb.x, d1 = r3 - lb.y;
        lossacc = pw.x*d0*d0 + pw.y*d1*d1;
    }

    // reduce loss across bsub bits (lane bits 3-5), then across the 16 waves
    #pragma unroll
    for (int off = 8; off <= 32; off <<= 1) lossacc += __shfl_xor(lossacc, off, 64);
    if (lane == 0) wloss[wave] = lossacc;
    __syncthreads();
    if (tid == 0) {
        float s = 0.f;
        #pragma unroll
        for (int i = 0; i < 16; ++i) s += wloss[i];
        partial[blockIdx.x] = s;
    }
}

// ---- tiny reduce: 256 block partials -> loss scalar ----
__global__ __launch_bounds__(256) void fm_loss(const float* __restrict__ partial,
                                               float* __restrict__ out) {
    const int tid = threadIdx.x;
    float v = partial[tid];
    #pragma unroll
    for (int off = 1; off <= 32; off <<= 1) v += __shfl_xor(v, off, 64);
    __shared__ float ws[4];
    if ((tid & 63) == 0) ws[tid >> 6] = v;
    __syncthreads();
    if (tid == 0) out[OUT_LOSS] = (ws[0]+ws[1]+ws[2]+ws[3]) * (1.0f/(float)NB);
}

extern "C" void kernel_launch(void* const* d_in, const int* in_sizes, int n_in,
                              void* d_out, int out_size, void* d_ws, size_t ws_size,
                              hipStream_t stream) {
    const int*   idx   = (const int*)d_in[0];
    const float* label = (const float*)d_in[1];
    const float* posw  = (const float*)d_in[2];
    const float* meant = (const float*)d_in[3];
    const float* stdt  = (const float*)d_in[4];
    const float* act   = (const float*)d_in[5];
    const float* noise = (const float*)d_in[6];
    float* out = (float*)d_out;
    float* partial = (float*)d_ws;   // 256 floats, fully written each call

    fm_main<<<256, 1024, 0, stream>>>(idx, label, posw, meant, stdt, act, noise, out, partial);
    fm_loss<<<1, 256, 0, stream>>>(partial, out);
}